// Round 16
// baseline (2664.590 us; speedup 1.0000x reference)
//
#include <hip/hip_runtime.h>
#include <hip/hip_bf16.h>

typedef __hip_bfloat16 bf16;
typedef unsigned short u16;
typedef __attribute__((ext_vector_type(8))) short s16x8;   // 8 bf16 (4 VGPRs) MFMA frag
typedef __attribute__((ext_vector_type(4))) float f32x4;   // MFMA accumulator

#define B_ 512
#define T_ 150
#define S_ 151
#define D_ 256
#define H_ 8
#define HD_ 32
#define FF_ 1024
#define NC_ 4
#define DEPTH_ 6
#define MTOT 77312            // B_*S_ = 128 * 604 = 64 * 1208
#define MT128 (MTOT / 128)    // 604
#define MT64 (MTOT / 64)      // 1208 = 151*8 (no swizzle tail)

// bf16 workspace regions (elements):
#define XOFF 0
#define C1OFF (MTOT * D_)               // x: MTOT*256
#define C2OFF (C1OFF + MTOT * FF_)      // c1: MTOT*1024 (qkv / ffn1 out)
#define WSELEMS (C2OFF + MTOT * D_)     // c2: MTOT*256 (attn out)

// Transposed bf16 weights Wt[N][K], all layers, rebuilt per call:
#define QKVT_OFF 0
#define OUTT_OFF (QKVT_OFF + DEPTH_ * D_ * 768)
#define FFN1T_OFF (OUTT_OFF + DEPTH_ * D_ * D_)
#define FFN2T_OFF (FFN1T_OFF + DEPTH_ * D_ * FF_)
#define WTELEMS (FFN2T_OFF + DEPTH_ * FF_ * D_)    // 9.4 MB

// Static device memory (d_ws proved unusable rounds 1-3).
__device__ __align__(16) u16 g_ws[WSELEMS];
__device__ __align__(16) u16 g_wt[WTELEMS];
__device__ int g_f32flag;   // 1 => external buffers f32, 0 => bf16

__device__ __forceinline__ float ldf(const void* p, size_t i, int f) {
  return f ? ((const float*)p)[i] : __bfloat162float(((const bf16*)p)[i]);
}
__device__ __forceinline__ float b2f(u16 u) {
  union { unsigned int i; float f; } v; v.i = ((unsigned int)u) << 16; return v.f;
}
__device__ __forceinline__ u16 f2b(float x) {
  bf16 h = __float2bfloat16(x);
  return *reinterpret_cast<u16*>(&h);
}

// Async global->LDS, 16 B/lane. LDS dest = wave-uniform base + lane*16.
typedef __attribute__((address_space(3))) void lds_void;
typedef const __attribute__((address_space(1))) void glob_void;
__device__ __forceinline__ void gload_lds16(const u16* g, u16* l) {
  __builtin_amdgcn_global_load_lds((glob_void*)g, (lds_void*)l, 16, 0, 0);
}

// ---------------------------------------------------------------------------
// Dtype probe on pos_embed (38656 elems ~N(0,0.02^2)) viewed as 16-bit words.
// ---------------------------------------------------------------------------
#define PROBE_N 38656
__global__ __launch_bounds__(256) void probe_kernel(const void* pe)
{
  const u16* w = (const u16*)pe;
  int susp = 0, zeroEven = 0;
  for (int k = threadIdx.x; k < PROBE_N; k += 256) {
    u16 u = w[k];
    int ex = (u >> 7) & 0xFF;
    if (ex >= 141) susp++;
    if ((k & 1) == 0 && (u & 0x7FFF) == 0) zeroEven++;
  }
  __shared__ int s_susp, s_zero;
  if (threadIdx.x == 0) { s_susp = 0; s_zero = 0; }
  __syncthreads();
  atomicAdd(&s_susp, susp);
  atomicAdd(&s_zero, zeroEven);
  __syncthreads();
  if (threadIdx.x == 0)
    g_f32flag = (s_susp > 0 || s_zero >= ((PROBE_N / 2) * 9) / 10) ? 1 : 0;
}

// ---------------------------------------------------------------------------
// Weight transpose+convert: Wt[l][n][k] = W[l][k][n] as bf16.
// ---------------------------------------------------------------------------
__global__ __launch_bounds__(256) void wtrans_kernel(const void* src, int dstOff,
                                                     int K, int N, int total)
{
  const int f = g_f32flag;
  int idx = blockIdx.x * 256 + threadIdx.x;
  if (idx >= total) return;
  int kn = K * N;
  int l = idx / kn;
  int r = idx - l * kn;
  int k = r / N;
  int n = r - k * N;
  g_wt[dstOff + (size_t)l * kn + (size_t)n * K + k] = f2b(ldf(src, idx, f));
}

// ---------------------------------------------------------------------------
// Embedding: row = blockIdx.x, writes bf16 x.
// ---------------------------------------------------------------------------
__global__ __launch_bounds__(256) void embed_kernel(
    const int* __restrict__ tt, const int* __restrict__ dids,
    const void* av, const void* dv, const void* vv,
    const void* aW, const void* ab, const void* dW, const void* db,
    const void* vW, const void* vb, const void* table, const void* pos,
    const void* cls)
{
  const int f = g_f32flag;
  u16* x = g_ws + XOFF;
  int row = blockIdx.x;
  int d = threadIdx.x;
  int b = row / S_;
  int s = row - b * S_;
  float val;
  if (s == 0) {
    val = ldf(cls, d, f);
  } else {
    int t = s - 1;
    int idx = b * T_ + t;
    int ty = tt[idx];
    if (ty == 0) {
      val = ldf(av, idx, f) * ldf(aW, d, f) + ldf(ab, d, f);
    } else if (ty == 1) {
      float acc = ldf(db, d, f) + ldf(vb, d, f);
#pragma unroll
      for (int i = 0; i < 10; i++) acc += ldf(dv, (size_t)idx * 10 + i, f) * ldf(dW, i * D_ + d, f);
#pragma unroll
      for (int i = 0; i < 3; i++) acc += ldf(vv, (size_t)idx * 3 + i, f) * ldf(vW, i * D_ + d, f);
      val = acc;
    } else if (ty == 2) {
      int did = dids[idx] & (NC_ - 1);
      val = ldf(table, (size_t)did * D_ + d, f);
    } else {
      val = 0.f;
    }
  }
  val += ldf(pos, s * D_ + d, f);
  x[(size_t)row * D_ + d] = f2b(val);
}

// ---------------------------------------------------------------------------
// MFMA GEMM, ROUND-16: 64x128 tile, BK=64, 256 thr = 4 waves side-by-side
// in N (each 64 rows x 32 cols, acc[4][2] = 32 AGPRs). Staging 24 KB,
// __launch_bounds__(256,5) -> 5 blocks/CU = 20 waves/CU (was 12 with the
// 128x128 tile). Same proven ingredients: global_load_lds w=16, xor-swizzled
// chunks (0 conflicts), XCD swizzle (1208 m-tiles = 151*8, no tail),
// LDS-staged coalesced epilogue. Used for qkv (N=768) and ffn1 (N=1024).
// ---------------------------------------------------------------------------
__global__ __launch_bounds__(256, 5) void gemm_mfma(
    int aOff, int wtOff, const void* bias, size_t bOff,
    int cOff, int N, int K, int relu, int NB)
{
  const int f = g_f32flag;
  const u16* A = g_ws + aOff;
  const u16* Bt = g_wt + wtOff;
  u16* C = g_ws + cOff;
  __shared__ __align__(16) u16 sm[12288];   // A 8KB | B 16KB; epilogue 64x136
  const int tid = threadIdx.x;

  // XCD swizzle: groups of 8 bm-rows x NB cols (1208 % 8 == 0 -> no tail).
  int gblk = blockIdx.x;
  const int per = NB * 8;
  const int grp0 = gblk / per, rem = gblk % per;
  const int bm = grp0 * 8 + (rem & 7);
  const int bn = rem >> 3;

  const int lane = tid & 63, wid = tid >> 6;
  const int wn = wid * 32;
  const int frow = lane & 15, quad = lane >> 4;

  const int rg = lane >> 3;
  const int ck = ((lane & 7) ^ rg) * 8;
  const u16* Ag[2]; const u16* Bg[4];
  u16 *Asl[2], *Bsl[4];
#pragma unroll
  for (int p = 0; p < 2; p++) {
    int grp = wid * 2 + p;                   // 0..8 -> A rows 0..63
    Ag[p] = A + (size_t)(bm * 64 + grp * 8 + rg) * K + ck;
    Asl[p] = &sm[grp * 512];
  }
#pragma unroll
  for (int p = 0; p < 4; p++) {
    int grp = wid * 4 + p;                   // 0..16 -> B rows 0..127
    Bg[p] = Bt + (size_t)(bn * 128 + grp * 8 + rg) * K + ck;
    Bsl[p] = &sm[4096 + grp * 512];
  }

  f32x4 acc[4][2] = {};

  for (int kt = 0; kt < K; kt += 64) {
    if (kt) __syncthreads();
#pragma unroll
    for (int p = 0; p < 2; p++) gload_lds16(Ag[p] + kt, Asl[p]);
#pragma unroll
    for (int p = 0; p < 4; p++) gload_lds16(Bg[p] + kt, Bsl[p]);
    __syncthreads();   // drains vmcnt: LDS data landed
#pragma unroll
    for (int s = 0; s < 2; s++) {
      s16x8 af[4], bfr[2];
      const int cfr = ((s * 4 + quad) ^ (frow & 7)) * 8;
#pragma unroll
      for (int t = 0; t < 4; t++)
        af[t] = *(const s16x8*)&sm[(t * 16 + frow) * 64 + cfr];
#pragma unroll
      for (int nt = 0; nt < 2; nt++)
        bfr[nt] = *(const s16x8*)&sm[4096 + (wn + nt * 16 + frow) * 64 + cfr];
#pragma unroll
      for (int mt = 0; mt < 4; mt++)
#pragma unroll
        for (int nt = 0; nt < 2; nt++)
          acc[mt][nt] = __builtin_amdgcn_mfma_f32_16x16x32_bf16(af[mt], bfr[nt], acc[mt][nt], 0, 0, 0);
    }
  }

  float bv[2];
#pragma unroll
  for (int nt = 0; nt < 2; nt++)
    bv[nt] = ldf(bias, bOff + (size_t)(bn * 128 + wn + nt * 16 + frow), f);
  __syncthreads();   // all frag reads done; reuse sm as C-tile 64x136
#pragma unroll
  for (int mt = 0; mt < 4; mt++)
#pragma unroll
    for (int nt = 0; nt < 2; nt++)
#pragma unroll
      for (int r = 0; r < 4; r++) {
        int rl = mt * 16 + quad * 4 + r;
        float v = acc[mt][nt][r] + bv[nt];
        if (relu) v = fmaxf(v, 0.f);
        sm[rl * 136 + wn + nt * 16 + frow] = f2b(v);
      }
  __syncthreads();
  {
    int rl = tid >> 2;                // 0..63
    int cq = (tid & 3) * 32;          // 32 cols per thread
    size_t gb = (size_t)(bm * 64 + rl) * N + bn * 128 + cq;
#pragma unroll
    for (int j = 0; j < 4; j++)
      *(s16x8*)(C + gb + j * 8) = *(const s16x8*)&sm[rl * 136 + cq + j * 8];
  }
}

// ---------------------------------------------------------------------------
// Fused-LN GEMM: x = LN(x + A@W + bias) * g + b. 64x256 tile, 256 thr =
// 4 waves side-by-side in N. Single-phase K-loop (round-12 lesson).
// (256,4): verified round 15 (VGPR 64, 4 blocks/CU).
// ---------------------------------------------------------------------------
__global__ __launch_bounds__(256, 4) void gemm_ln(
    int aOff, int wtOff, const void* bias, size_t bOff,
    const void* lng, const void* lnb, size_t lnOff, int K)
{
  const int f = g_f32flag;
  const u16* A = g_ws + aOff;
  const u16* Bt = g_wt + wtOff;
  __shared__ __align__(16) u16 sm[20480];   // A 8KB | B 32KB; epilogue 64x264
  const int tid = threadIdx.x;
  const int bm = blockIdx.x;                // 64-row tile
  const int lane = tid & 63, wid = tid >> 6;
  const int wn = wid * 64;
  const int frow = lane & 15, quad = lane >> 4;
  const int rg = lane >> 3;
  const int ck = ((lane & 7) ^ rg) * 8;

  const u16* Ag[2]; u16* Asl[2];
  const u16* Bg[8]; u16* Bsl[8];
#pragma unroll
  for (int p = 0; p < 2; p++) {
    int grp = wid * 2 + p;                  // 0..8: rows 0..63
    Ag[p] = A + (size_t)(bm * 64 + grp * 8 + rg) * K + ck;
    Asl[p] = &sm[grp * 512];
  }
#pragma unroll
  for (int p = 0; p < 8; p++) {
    int grp = wid * 8 + p;                  // 0..32: Wt rows 0..255
    Bg[p] = Bt + (size_t)(grp * 8 + rg) * K + ck;
    Bsl[p] = &sm[4096 + grp * 512];
  }

  f32x4 acc[4][4] = {};

  for (int kt = 0; kt < K; kt += 64) {
    if (kt) __syncthreads();
#pragma unroll
    for (int p = 0; p < 2; p++) gload_lds16(Ag[p] + kt, Asl[p]);
#pragma unroll
    for (int p = 0; p < 8; p++) gload_lds16(Bg[p] + kt, Bsl[p]);
    __syncthreads();
#pragma unroll
    for (int s = 0; s < 2; s++) {
      s16x8 af[4], bfr[4];
      const int cfr = ((s * 4 + quad) ^ (frow & 7)) * 8;
#pragma unroll
      for (int t = 0; t < 4; t++) {
        af[t]  = *(const s16x8*)&sm[(t * 16 + frow) * 64 + cfr];
        bfr[t] = *(const s16x8*)&sm[4096 + (wn + t * 16 + frow) * 64 + cfr];
      }
#pragma unroll
      for (int mt = 0; mt < 4; mt++)
#pragma unroll
        for (int nt = 0; nt < 4; nt++)
          acc[mt][nt] = __builtin_amdgcn_mfma_f32_16x16x32_bf16(af[mt], bfr[nt], acc[mt][nt], 0, 0, 0);
    }
  }

  float bv[4];
#pragma unroll
  for (int nt = 0; nt < 4; nt++)
    bv[nt] = ldf(bias, bOff + (size_t)(wn + nt * 16 + frow), f);
  __syncthreads();   // all frag reads done; reuse sm as y-buf 64x264
#pragma unroll
  for (int mt = 0; mt < 4; mt++)
#pragma unroll
    for (int nt = 0; nt < 4; nt++)
#pragma unroll
      for (int r = 0; r < 4; r++) {
        int row = mt * 16 + quad * 4 + r;
        int col = wn + nt * 16 + frow;
        sm[row * 264 + col] = f2b(acc[mt][nt][r] + bv[nt]);
      }
  __syncthreads();
  {
    int rl = tid >> 2;                 // row 0..63 (4 lanes per row)
    int cq = (tid & 3) * 64;           // 64 cols per lane
    size_t rowg = (size_t)bm * 64 + rl;
    float s1 = 0.f, s2 = 0.f;
#pragma unroll
    for (int j = 0; j < 8; j++) {
      s16x8 yv = *(const s16x8*)&sm[rl * 264 + cq + j * 8];
      s16x8 xv = *(const s16x8*)(g_ws + XOFF + rowg * 256 + cq + j * 8);
#pragma unroll
      for (int e = 0; e < 8; e++) {
        float v = b2f((u16)yv[e]) + b2f((u16)xv[e]);
        s1 += v; s2 += v * v;
      }
    }
    s1 += __shfl_xor(s1, 1, 64); s2 += __shfl_xor(s2, 1, 64);
    s1 += __shfl_xor(s1, 2, 64); s2 += __shfl_xor(s2, 2, 64);
    float mean = s1 * (1.f / 256.f);
    float var = s2 * (1.f / 256.f) - mean * mean;
    float rs = rsqrtf(var + 1e-5f);
#pragma unroll
    for (int j = 0; j < 8; j++) {
      s16x8 yv = *(const s16x8*)&sm[rl * 264 + cq + j * 8];
      s16x8 xv = *(const s16x8*)(g_ws + XOFF + rowg * 256 + cq + j * 8);
      s16x8 ov;
#pragma unroll
      for (int e = 0; e < 8; e++) {
        float v = b2f((u16)yv[e]) + b2f((u16)xv[e]);
        int col = cq + j * 8 + e;
        ov[e] = (short)f2b((v - mean) * rs * ldf(lng, lnOff + col, f) + ldf(lnb, lnOff + col, f));
      }
      *(s16x8*)(g_ws + XOFF + rowg * 256 + cq + j * 8) = ov;
    }
  }
}

// ---------------------------------------------------------------------------
// MFMA attention (S=151 padded 160). K via global_load_lds (round-14),
// interleaved P-transpose through small wave-private buffer (round-15,
// 27.8 KB LDS -> 5 blocks/CU).
// ---------------------------------------------------------------------------
#define SP 160
#define KLD 32
#define VLD 170
#define PLDS 42

__global__ __launch_bounds__(320) void attn_kernel()
{
  const u16* qkv = g_ws + C1OFF;
  u16* o = g_ws + C2OFF;
  __shared__ __align__(16) u16 Ks[SP * KLD];        // 10240 B
  __shared__ __align__(16) u16 Vt[HD_ * VLD];       // 10880 B
  __shared__ __align__(16) u16 Ps[5][16 * PLDS];    // 6720 B
  int bh = blockIdx.x;
  int b = bh >> 3, h = bh & 7;
  int tid = threadIdx.x;
  int lane = tid & 63, wid = tid >> 6;
  const u16* base = qkv + (size_t)b * S_ * 768;

  {
    const int jrow = lane >> 2;
    const int dsw = (((lane & 3) ^ ((lane >> 3) & 3)) * 8);
#pragma unroll
    for (int p = 0; p < 2; p++) {
      int g = wid * 2 + p;                 // 0..9
      int j = g * 16 + jrow;               // 0..159; tail rows masked later
      gload_lds16(base + (size_t)j * 768 + 256 + h * 32 + dsw, &Ks[g * 512]);
    }
  }
  for (int g = tid; g < SP * 4; g += 320) {
    int j = g >> 2, d0 = (g & 3) * 8;
    s16x8 vv = {0, 0, 0, 0, 0, 0, 0, 0};
    if (j < S_) vv = *(const s16x8*)(base + (size_t)j * 768 + 512 + h * 32 + d0);
#pragma unroll
    for (int i = 0; i < 8; i++) Vt[(d0 + i) * VLD + j] = (u16)vv[i];
  }
  __syncthreads();

  const int frow = lane & 15;
  const int quad = lane >> 4;
  const int fk = quad * 8;
  const float scale = 0.17677669529663687f;  // 1/sqrt(32)
  u16* Pw = &Ps[wid][0];

  for (int round = 0; round < 2; round++) {
    int mt = round * 5 + wid;
    int qrow = mt * 16 + frow;
    s16x8 aq = {0, 0, 0, 0, 0, 0, 0, 0};
    if (qrow < S_) aq = *(const s16x8*)(base + (size_t)qrow * 768 + h * 32 + fk);
    f32x4 sacc[10];
#pragma unroll
    for (int nt = 0; nt < 10; nt++) {
      s16x8 bk = *(const s16x8*)&Ks[(nt * 16 + frow) * KLD
                                    + ((quad ^ ((frow >> 1) & 3)) * 8)];
      f32x4 z = {0.f, 0.f, 0.f, 0.f};
      sacc[nt] = __builtin_amdgcn_mfma_f32_16x16x32_bf16(aq, bk, z, 0, 0, 0);
    }
#pragma unroll
    for (int nt = 0; nt < 10; nt++) {
      int colg = nt * 16 + frow;
      float msk = (colg < S_) ? 1.f : 0.f;
#pragma unroll
      for (int r = 0; r < 4; r++)
        sacc[nt][r] = msk ? sacc[nt][r] * scale : -1e30f;
    }
    float inv[4];
#pragma unroll
    for (int r = 0; r < 4; r++) {
      float mx = -1e30f;
#pragma unroll
      for (int nt = 0; nt < 10; nt++) mx = fmaxf(mx, sacc[nt][r]);
#pragma unroll
      for (int m = 1; m < 16; m <<= 1) mx = fmaxf(mx, __shfl_xor(mx, m, 64));
      float sm2 = 0.f;
#pragma unroll
      for (int nt = 0; nt < 10; nt++) {
        float p = __expf(sacc[nt][r] - mx);
        sacc[nt][r] = p;
        sm2 += p;
      }
#pragma unroll
      for (int m = 1; m < 16; m <<= 1) sm2 += __shfl_xor(sm2, m, 64);
      inv[r] = 1.f / sm2;
    }
    f32x4 oacc[2] = {};
#pragma unroll
    for (int ks = 0; ks < 5; ks++) {
#pragma unroll
      for (int h2 = 0; h2 < 2; h2++) {
        int nt = ks * 2 + h2;
#pragma unroll
        for (int r = 0; r < 4; r++)
          Pw[(quad * 4 + r) * PLDS + h2 * 16 + frow] = f2b(sacc[nt][r]);
      }
      s16x8 ap = *(const s16x8*)&Pw[frow * PLDS + fk];
#pragma unroll
      for (int nt2 = 0; nt2 < 2; nt2++) {
        s16x8 bv = *(const s16x8*)&Vt[(nt2 * 16 + frow) * VLD + ks * 32 + fk];
        oacc[nt2] = __builtin_amdgcn_mfma_f32_16x16x32_bf16(ap, bv, oacc[nt2], 0, 0, 0);
      }
    }
#pragma unroll
    for (int nt2 = 0; nt2 < 2; nt2++)
#pragma unroll
      for (int r = 0; r < 4; r++) {
        int rowg = mt * 16 + quad * 4 + r;
        if (rowg < S_)
          o[(size_t)(b * S_ + rowg) * D_ + h * 32 + nt2 * 16 + frow] = f2b(oacc[nt2][r] * inv[r]);
      }
  }
}

// ---------------------------------------------------------------------------
// Head: cls row -> two LNs (shared stats) -> two tiny matvecs.
// ---------------------------------------------------------------------------
__global__ __launch_bounds__(256) void head_kernel(
    const void* dg, const void* dbt, const void* dW, const void* dbias,
    const void* ag, const void* abt, const void* aW, const void* abias,
    void* out)
{
  const int f = g_f32flag;
  const u16* x = g_ws + XOFF;
  int bg = blockIdx.x;
  int tid = threadIdx.x;
  float c = b2f(x[(size_t)bg * S_ * D_ + tid]);
  float s1 = c, s2 = c * c;
#pragma unroll
  for (int off = 32; off > 0; off >>= 1) {
    s1 += __shfl_down(s1, off, 64);
    s2 += __shfl_down(s2, off, 64);
  }
  __shared__ float ws1[4], ws2[4], stats[2];
  __shared__ float lnD[256], lnA[256];
  int wid = tid >> 6, lane = tid & 63;
  if (lane == 0) { ws1[wid] = s1; ws2[wid] = s2; }
  __syncthreads();
  if (tid == 0) {
    float t1 = ws1[0] + ws1[1] + ws1[2] + ws1[3];
    float t2 = ws2[0] + ws2[1] + ws2[2] + ws2[3];
    float mean = t1 * (1.f / 256.f);
    float var = t2 * (1.f / 256.f) - mean * mean;
    stats[0] = mean;
    stats[1] = rsqrtf(var + 1e-5f);
  }
  __syncthreads();
  float n = (c - stats[0]) * stats[1];
  lnD[tid] = n * ldf(dg, tid, f) + ldf(dbt, tid, f);
  lnA[tid] = n * ldf(ag, tid, f) + ldf(abt, tid, f);
  __syncthreads();
  if (tid < NC_) {
    float acc = ldf(dbias, tid, f);
    for (int k = 0; k < D_; k++) acc += lnD[k] * ldf(dW, k * NC_ + tid, f);
    if (f) ((float*)out)[bg * NC_ + tid] = acc;
    else   ((bf16*)out)[bg * NC_ + tid] = __float2bfloat16(acc);
  } else if (tid == 8) {
    float acc = ldf(abias, 0, f);
    for (int k = 0; k < D_; k++) acc += lnA[k] * ldf(aW, k, f);
    if (f) ((float*)out)[B_ * NC_ + bg] = acc;
    else   ((bf16*)out)[B_ * NC_ + bg] = __float2bfloat16(acc);
  }
}

// ---------------------------------------------------------------------------
extern "C" void kernel_launch(void* const* d_in, const int* in_sizes, int n_in,
                              void* d_out, int out_size, void* d_ws, size_t ws_size,
                              hipStream_t stream)
{
  (void)in_sizes; (void)out_size; (void)d_ws; (void)ws_size;
  if (n_in < 34) return;
  const int* token_types  = (const int*)d_in[0];
  const int* decision_ids = (const int*)d_in[1];

  probe_kernel<<<1, 256, 0, stream>>>(d_in[12]);   // pos_embed

  wtrans_kernel<<<(DEPTH_ * D_ * 768 + 255) / 256, 256, 0, stream>>>(
      d_in[14], QKVT_OFF, D_, 768, DEPTH_ * D_ * 768);
  wtrans_kernel<<<(DEPTH_ * D_ * D_ + 255) / 256, 256, 0, stream>>>(
      d_in[16], OUTT_OFF, D_, D_, DEPTH_ * D_ * D_);
  wtrans_kernel<<<(DEPTH_ * D_ * FF_ + 255) / 256, 256, 0, stream>>>(
      d_in[22], FFN1T_OFF, D_, FF_, DEPTH_ * D_ * FF_);
  wtrans_kernel<<<(DEPTH_ * FF_ * D_ + 255) / 256, 256, 0, stream>>>(
      d_in[24], FFN2T_OFF, FF_, D_, DEPTH_ * FF_ * D_);

  embed_kernel<<<MTOT, 256, 0, stream>>>(token_types, decision_ids,
      d_in[2], d_in[3], d_in[4], d_in[5], d_in[6], d_in[7], d_in[8],
      d_in[9], d_in[10], d_in[11], d_in[12], d_in[13]);

  for (int i = 0; i < DEPTH_; i++) {
    gemm_mfma<<<6 * MT64, 256, 0, stream>>>(XOFF,
        QKVT_OFF + i * D_ * 768, d_in[15], (size_t)i * 768, C1OFF, 768, D_, 0, 6);
    attn_kernel<<<B_ * H_, 320, 0, stream>>>();
    // out-proj fused: x = LN1(x + attn_out @ Wout + b)
    gemm_ln<<<MT64, 256, 0, stream>>>(C2OFF,
        OUTT_OFF + i * D_ * D_, d_in[17], (size_t)i * D_,
        d_in[18], d_in[19], (size_t)i * D_, D_);
    gemm_mfma<<<8 * MT64, 256, 0, stream>>>(XOFF,
        FFN1T_OFF + i * D_ * FF_, d_in[23], (size_t)i * FF_, C1OFF, FF_, D_, 1, 8);
    // ffn2 fused: x = LN2(x + ff @ W2 + b)
    gemm_ln<<<MT64, 256, 0, stream>>>(C1OFF,
        FFN2T_OFF + i * FF_ * D_, d_in[25], (size_t)i * D_,
        d_in[20], d_in[21], (size_t)i * D_, FF_);
  }
  head_kernel<<<B_, 256, 0, stream>>>(d_in[26], d_in[27], d_in[28], d_in[29],
      d_in[30], d_in[31], d_in[32], d_in[33], d_out);
}